// Round 1
// baseline (968.655 us; speedup 1.0000x reference)
//
#include <hip/hip_runtime.h>

#define N_NODES 50000
#define N_EDGES 800000
#define HID 64

// ---------------- CSR build ----------------

__global__ void k_deg(const int* __restrict__ dst, int* __restrict__ deg, int n) {
    int e = blockIdx.x * blockDim.x + threadIdx.x;
    if (e < n) atomicAdd(&deg[dst[e]], 1);
}

__global__ void k_norm(const int* __restrict__ deg, float* __restrict__ norm, int n) {
    int i = blockIdx.x * blockDim.x + threadIdx.x;
    if (i < n) {
        float d = (float)deg[i];
        norm[i] = 1.0f / sqrtf(fmaxf(d, 1.0f));
    }
}

__global__ __launch_bounds__(1024) void k_scan(const int* __restrict__ deg,
                                               int* __restrict__ row_ptr,
                                               int* __restrict__ cursor, int n) {
    __shared__ int lds[1024];
    __shared__ int carry_s;
    int tid = threadIdx.x;
    if (tid == 0) carry_s = 0;
    __syncthreads();
    for (int base = 0; base < n; base += 1024) {
        int i = base + tid;
        int v = (i < n) ? deg[i] : 0;
        lds[tid] = v;
        __syncthreads();
        for (int off = 1; off < 1024; off <<= 1) {
            int t = (tid >= off) ? lds[tid - off] : 0;
            __syncthreads();
            lds[tid] += t;
            __syncthreads();
        }
        int incl = lds[tid];
        int c = carry_s;
        __syncthreads();          // everyone has read carry_s + lds
        if (i < n) {
            int ex = c + incl - v;
            row_ptr[i] = ex;
            cursor[i]  = ex;
        }
        if (tid == 1023) carry_s = c + incl;
        __syncthreads();
    }
    if (tid == 0) row_ptr[n] = carry_s;
}

__global__ void k_scatter(const int* __restrict__ src, const int* __restrict__ dst,
                          int* __restrict__ cursor, int* __restrict__ csr_src, int n) {
    int e = blockIdx.x * blockDim.x + threadIdx.x;
    if (e < n) {
        int d = dst[e];
        int pos = atomicAdd(&cursor[d], 1);
        csr_src[pos] = src[e];
    }
}

// ---------------- GCN layer 0 (2-dim input, folded) ----------------
// agg0 = (sum nf[src]*norm[src]) @ W0 + b0 * (sum norm[src]); h0 = relu(agg0*norm)

__global__ void k_aggnf(const float2* __restrict__ nf, const float* __restrict__ norm,
                        const int* __restrict__ row_ptr, const int* __restrict__ csr_src,
                        float2* __restrict__ aggnf, float* __restrict__ snorm, int n_nodes) {
    int nd = blockIdx.x * blockDim.x + threadIdx.x;
    if (nd < n_nodes) {
        int r0 = row_ptr[nd], r1 = row_ptr[nd + 1];
        float a0 = 0.f, a1 = 0.f, sn = 0.f;
        for (int i = r0; i < r1; ++i) {
            int s = csr_src[i];
            float ns = norm[s];
            float2 v = nf[s];
            a0 += v.x * ns;
            a1 += v.y * ns;
            sn += ns;
        }
        aggnf[nd] = make_float2(a0, a1);
        snorm[nd] = sn;
    }
}

__global__ void k_h0(const float2* __restrict__ aggnf, const float* __restrict__ snorm,
                     const float* __restrict__ norm, const float* __restrict__ W0,
                     const float* __restrict__ b0, float* __restrict__ h, int total) {
    int idx = blockIdx.x * blockDim.x + threadIdx.x;
    if (idx < total) {
        int n = idx >> 6, j = idx & 63;
        float2 a = aggnf[n];
        float v = (a.x * W0[j] + a.y * W0[64 + j] + b0[j] * snorm[n]) * norm[n];
        h[idx] = fmaxf(v, 0.f);
    }
}

// ---------------- GCN layers 1/2, fused: aggregate h, then 64x64 matvec ----------------
// out = relu(((sum h[src]*norm[src]) @ W + b*snorm) * norm) + h   (residual)

__global__ __launch_bounds__(256) void k_layer(const float* __restrict__ h_in,
                                               float* __restrict__ h_out,
                                               const float* __restrict__ W,
                                               const float* __restrict__ b,
                                               const float* __restrict__ norm,
                                               const float* __restrict__ snorm,
                                               const int* __restrict__ row_ptr,
                                               const int* __restrict__ csr_src,
                                               int n_nodes) {
    __shared__ float xs[4][64];
    const int lane = threadIdx.x & 63;
    const int wid  = threadIdx.x >> 6;
    float w[64];
#pragma unroll
    for (int k = 0; k < 64; ++k) w[k] = W[k * 64 + lane];
    float bj = b[lane];
    int wg = blockIdx.x * 4 + wid;
    int nw = gridDim.x * 4;
    for (int n = wg; n < n_nodes; n += nw) {
        int r0 = row_ptr[n], r1 = row_ptr[n + 1];
        float acc = 0.f;
        for (int i = r0; i < r1; ++i) {
            int s = csr_src[i];
            acc += h_in[s * 64 + lane] * norm[s];
        }
        xs[wid][lane] = acc;
        asm volatile("s_waitcnt lgkmcnt(0)" ::: "memory");
        float o = bj * snorm[n];
#pragma unroll
        for (int k = 0; k < 64; ++k) o += xs[wid][k] * w[k];
        o = fmaxf(o * norm[n], 0.f) + h_in[n * 64 + lane];
        h_out[n * 64 + lane] = o;
    }
}

// ---------------- per-node matvec: out[n] = h[n] @ Wpart (64x64) ----------------

__global__ __launch_bounds__(256) void k_matvec(const float* __restrict__ hin,
                                                const float* __restrict__ Wpart,
                                                float* __restrict__ outbuf, int n_nodes) {
    __shared__ float xs[4][64];
    const int lane = threadIdx.x & 63;
    const int wid  = threadIdx.x >> 6;
    float w[64];
#pragma unroll
    for (int k = 0; k < 64; ++k) w[k] = Wpart[k * 64 + lane];
    int wg = blockIdx.x * 4 + wid;
    int nw = gridDim.x * 4;
    for (int n = wg; n < n_nodes; n += nw) {
        xs[wid][lane] = hin[n * 64 + lane];
        asm volatile("s_waitcnt lgkmcnt(0)" ::: "memory");
        float o = 0.f;
#pragma unroll
        for (int k = 0; k < 64; ++k) o += xs[wid][k] * w[k];
        outbuf[n * 64 + lane] = o;
    }
}

// ---------------- tiny embedding projections ----------------
// C1 = curr_emb @ M0[128:136], C2 = curr_emb @ M0[136:144], P = pay_emb @ M0[144:148]

__global__ void k_small(const float* __restrict__ curr_emb, const float* __restrict__ pay_emb,
                        const float* __restrict__ M0, float* __restrict__ C1,
                        float* __restrict__ C2, float* __restrict__ P) {
    int tid = threadIdx.x;
    for (int idx = tid; idx < 15 * 64; idx += blockDim.x) {
        int c = idx >> 6, j = idx & 63;
        float s1 = 0.f, s2 = 0.f;
        for (int k = 0; k < 8; ++k) {
            float ce = curr_emb[c * 8 + k];
            s1 += ce * M0[(128 + k) * 64 + j];
            s2 += ce * M0[(136 + k) * 64 + j];
        }
        C1[idx] = s1;
        C2[idx] = s2;
    }
    for (int idx = tid; idx < 7 * 64; idx += blockDim.x) {
        int p = idx >> 6, j = idx & 63;
        float s = 0.f;
        for (int k = 0; k < 4; ++k) s += pay_emb[p * 4 + k] * M0[(144 + k) * 64 + j];
        P[idx] = s;
    }
}

// ---------------- edge MLP ----------------
// x0 = relu(A[src] + B[dst] + C1[pc] + C2[rc] + P[pf] + num@M0n + bM0)
// x1 = relu(x0 @ M1 + bM1); logits = x1 @ M2 + bM2

__global__ __launch_bounds__(256) void k_edge(const float* __restrict__ A,
                                              const float* __restrict__ B,
                                              const float* __restrict__ C1,
                                              const float* __restrict__ C2,
                                              const float* __restrict__ P,
                                              const float* __restrict__ M0,
                                              const float* __restrict__ bM0,
                                              const float* __restrict__ M1,
                                              const float* __restrict__ bM1,
                                              const float* __restrict__ M2,
                                              const float* __restrict__ bM2,
                                              const int* __restrict__ src,
                                              const int* __restrict__ dst,
                                              const int* __restrict__ pc,
                                              const int* __restrict__ rc,
                                              const int* __restrict__ pf,
                                              const float* __restrict__ num,
                                              float* __restrict__ out, int n_edges) {
    __shared__ float xs[4][64];
    const int lane = threadIdx.x & 63;
    const int wid  = threadIdx.x >> 6;
    float m1[64];
#pragma unroll
    for (int k = 0; k < 64; ++k) m1[k] = M1[k * 64 + lane];
    float m0n[5];
#pragma unroll
    for (int k = 0; k < 5; ++k) m0n[k] = M0[(148 + k) * 64 + lane];
    float bm0 = bM0[lane], bm1 = bM1[lane];
    float m2a = M2[lane * 2 + 0], m2b = M2[lane * 2 + 1];
    float bm2a = bM2[0], bm2b = bM2[1];
    int wg = blockIdx.x * 4 + wid;
    int nw = gridDim.x * 4;
    for (int e = wg; e < n_edges; e += nw) {
        int s = src[e], d = dst[e];
        int c1 = pc[e], c2 = rc[e], p = pf[e];
        float x0 = A[s * 64 + lane] + B[d * 64 + lane] + C1[c1 * 64 + lane]
                 + C2[c2 * 64 + lane] + P[p * 64 + lane] + bm0;
#pragma unroll
        for (int k = 0; k < 5; ++k) x0 += num[e * 5 + k] * m0n[k];
        x0 = fmaxf(x0, 0.f);
        xs[wid][lane] = x0;
        asm volatile("s_waitcnt lgkmcnt(0)" ::: "memory");
        float x1 = bm1;
#pragma unroll
        for (int k = 0; k < 64; ++k) x1 += xs[wid][k] * m1[k];
        x1 = fmaxf(x1, 0.f);
        float p0 = x1 * m2a, p1 = x1 * m2b;
#pragma unroll
        for (int off = 32; off; off >>= 1) {
            p0 += __shfl_xor(p0, off);
            p1 += __shfl_xor(p1, off);
        }
        if (lane == 0) {
            out[e * 2 + 0] = p0 + bm2a;
            out[e * 2 + 1] = p1 + bm2b;
        }
    }
}

// ---------------- launch ----------------

extern "C" void kernel_launch(void* const* d_in, const int* in_sizes, int n_in,
                              void* d_out, int out_size, void* d_ws, size_t ws_size,
                              hipStream_t stream) {
    const float2* node_feats = (const float2*)d_in[0];
    const int*   src  = (const int*)d_in[1];
    const int*   dst  = (const int*)d_in[2];
    const int*   pc   = (const int*)d_in[3];
    const int*   rc   = (const int*)d_in[4];
    const int*   pf   = (const int*)d_in[5];
    const float* num  = (const float*)d_in[6];
    const float* W0   = (const float*)d_in[7];
    const float* b0   = (const float*)d_in[8];
    const float* W1   = (const float*)d_in[9];
    const float* b1   = (const float*)d_in[10];
    const float* W2   = (const float*)d_in[11];
    const float* b2   = (const float*)d_in[12];
    const float* curr_emb = (const float*)d_in[13];
    const float* pay_emb  = (const float*)d_in[14];
    const float* M0   = (const float*)d_in[15];
    const float* bM0  = (const float*)d_in[16];
    const float* M1   = (const float*)d_in[17];
    const float* bM1  = (const float*)d_in[18];
    const float* M2   = (const float*)d_in[19];
    const float* bM2  = (const float*)d_in[20];
    float* out = (float*)d_out;

    char* w = (char*)d_ws;
    auto alloc = [&](size_t bytes) {
        char* p = w;
        w += (bytes + 255) & ~size_t(255);
        return p;
    };
    int*    deg     = (int*)alloc(N_NODES * 4);
    float*  norm    = (float*)alloc(N_NODES * 4);
    float*  snorm   = (float*)alloc(N_NODES * 4);
    float2* aggnf   = (float2*)alloc(N_NODES * 8);
    int*    row_ptr = (int*)alloc((N_NODES + 1) * 4);
    int*    cursor  = (int*)alloc(N_NODES * 4);
    int*    csr_src = (int*)alloc(N_EDGES * 4);
    float*  buf0    = (float*)alloc(N_NODES * HID * 4);
    float*  buf1    = (float*)alloc(N_NODES * HID * 4);
    float*  bufA    = (float*)alloc(N_NODES * HID * 4);
    float*  C1      = (float*)alloc(15 * 64 * 4);
    float*  C2      = (float*)alloc(15 * 64 * 4);
    float*  P       = (float*)alloc(7 * 64 * 4);

    hipMemsetAsync(deg, 0, N_NODES * 4, stream);
    k_deg<<<(N_EDGES + 255) / 256, 256, 0, stream>>>(dst, deg, N_EDGES);
    k_norm<<<(N_NODES + 255) / 256, 256, 0, stream>>>(deg, norm, N_NODES);
    k_scan<<<1, 1024, 0, stream>>>(deg, row_ptr, cursor, N_NODES);
    k_scatter<<<(N_EDGES + 255) / 256, 256, 0, stream>>>(src, dst, cursor, csr_src, N_EDGES);
    k_aggnf<<<(N_NODES + 255) / 256, 256, 0, stream>>>(node_feats, norm, row_ptr, csr_src,
                                                       aggnf, snorm, N_NODES);
    k_h0<<<(N_NODES * HID + 255) / 256, 256, 0, stream>>>(aggnf, snorm, norm, W0, b0, buf0,
                                                          N_NODES * HID);
    k_layer<<<1536, 256, 0, stream>>>(buf0, buf1, W1, b1, norm, snorm, row_ptr, csr_src, N_NODES);
    k_layer<<<1536, 256, 0, stream>>>(buf1, buf0, W2, b2, norm, snorm, row_ptr, csr_src, N_NODES);
    k_small<<<1, 256, 0, stream>>>(curr_emb, pay_emb, M0, C1, C2, P);
    k_matvec<<<1536, 256, 0, stream>>>(buf0, M0, bufA, N_NODES);           // A = h @ M0[0:64]
    k_matvec<<<1536, 256, 0, stream>>>(buf0, M0 + 64 * 64, buf1, N_NODES); // B = h @ M0[64:128]
    k_edge<<<1536, 256, 0, stream>>>(bufA, buf1, C1, C2, P, M0, bM0, M1, bM1, M2, bM2,
                                     src, dst, pc, rc, pf, num, out, N_EDGES);
}

// Round 2
// 917.834 us; speedup vs baseline: 1.0554x; 1.0554x over previous
//
#include <hip/hip_runtime.h>

#define N_NODES 50000
#define N_EDGES 800000
#define HID 64

__device__ __forceinline__ float bf2f(unsigned short u) {
    union { unsigned int i; float f; } v;
    v.i = ((unsigned int)u) << 16;
    return v.f;
}
__device__ __forceinline__ unsigned short f2bf(float f) {
    union { float f; unsigned int i; } v;
    v.f = f;
    unsigned int b = v.i;
    return (unsigned short)((b + 0x7FFFu + ((b >> 16) & 1u)) >> 16);
}

// ---------------- CSR build ----------------

__global__ void k_deg(const int* __restrict__ dst, int* __restrict__ deg, int n) {
    int e = blockIdx.x * blockDim.x + threadIdx.x;
    if (e < n) atomicAdd(&deg[dst[e]], 1);
}

__global__ void k_norm(const int* __restrict__ deg, float* __restrict__ norm, int n) {
    int i = blockIdx.x * blockDim.x + threadIdx.x;
    if (i < n) {
        float d = (float)deg[i];
        norm[i] = 1.0f / sqrtf(fmaxf(d, 1.0f));
    }
}

__global__ __launch_bounds__(1024) void k_scan(const int* __restrict__ deg,
                                               int* __restrict__ row_ptr,
                                               int* __restrict__ cursor, int n) {
    __shared__ int lds[1024];
    __shared__ int carry_s;
    int tid = threadIdx.x;
    if (tid == 0) carry_s = 0;
    __syncthreads();
    for (int base = 0; base < n; base += 1024) {
        int i = base + tid;
        int v = (i < n) ? deg[i] : 0;
        lds[tid] = v;
        __syncthreads();
        for (int off = 1; off < 1024; off <<= 1) {
            int t = (tid >= off) ? lds[tid - off] : 0;
            __syncthreads();
            lds[tid] += t;
            __syncthreads();
        }
        int incl = lds[tid];
        int c = carry_s;
        __syncthreads();
        if (i < n) {
            int ex = c + incl - v;
            row_ptr[i] = ex;
            cursor[i]  = ex;
        }
        if (tid == 1023) carry_s = c + incl;
        __syncthreads();
    }
    if (tid == 0) row_ptr[n] = carry_s;
}

__global__ void k_scatter(const int* __restrict__ src, const int* __restrict__ dst,
                          int* __restrict__ cursor, int* __restrict__ csr_src, int n) {
    int e = blockIdx.x * blockDim.x + threadIdx.x;
    if (e < n) {
        int d = dst[e];
        int pos = atomicAdd(&cursor[d], 1);
        csr_src[pos] = src[e];
    }
}

// ---------------- GCN layer 0 (2-dim input, folded) ----------------

__global__ void k_aggnf(const float2* __restrict__ nf, const float* __restrict__ norm,
                        const int* __restrict__ row_ptr, const int* __restrict__ csr_src,
                        float2* __restrict__ aggnf, float* __restrict__ snorm, int n_nodes) {
    int nd = blockIdx.x * blockDim.x + threadIdx.x;
    if (nd < n_nodes) {
        int r0 = row_ptr[nd], r1 = row_ptr[nd + 1];
        float a0 = 0.f, a1 = 0.f, sn = 0.f;
        for (int i = r0; i < r1; ++i) {
            int s = csr_src[i];
            float ns = norm[s];
            float2 v = nf[s];
            a0 += v.x * ns;
            a1 += v.y * ns;
            sn += ns;
        }
        aggnf[nd] = make_float2(a0, a1);
        snorm[nd] = sn;
    }
}

__global__ void k_h0(const float2* __restrict__ aggnf, const float* __restrict__ snorm,
                     const float* __restrict__ norm, const float* __restrict__ W0,
                     const float* __restrict__ b0, float* __restrict__ h, int total) {
    int idx = blockIdx.x * blockDim.x + threadIdx.x;
    if (idx < total) {
        int n = idx >> 6, j = idx & 63;
        float2 a = aggnf[n];
        float v = (a.x * W0[j] + a.y * W0[64 + j] + b0[j] * snorm[n]) * norm[n];
        h[idx] = fmaxf(v, 0.f);
    }
}

// ---------------- GCN layers 1/2 ----------------
// out = relu(((sum h[src]*norm[src]) @ W + b*snorm) * norm) + h_in

__global__ __launch_bounds__(256) void k_layer(const float* __restrict__ h_in,
                                               float* __restrict__ h_out,
                                               const float* __restrict__ W,
                                               const float* __restrict__ b,
                                               const float* __restrict__ norm,
                                               const float* __restrict__ snorm,
                                               const int* __restrict__ row_ptr,
                                               const int* __restrict__ csr_src,
                                               int n_nodes) {
    __shared__ float xs[4][64];
    const int lane = threadIdx.x & 63;
    const int wid  = threadIdx.x >> 6;
    float w[64];
#pragma unroll
    for (int k = 0; k < 64; ++k) w[k] = W[k * 64 + lane];
    const float bj = b[lane];
    const int wg = blockIdx.x * 4 + wid;
    const int nw = gridDim.x * 4;
    const int niter = (n_nodes + nw - 1) / nw;
    for (int it = 0; it < niter; ++it) {
        const int n = wg + it * nw;
        if (n < n_nodes) {
            int r0 = row_ptr[n], r1 = row_ptr[n + 1];
            float acc = 0.f;
#pragma unroll 2
            for (int i = r0; i < r1; ++i) {
                int s = csr_src[i];
                acc += h_in[s * 64 + lane] * norm[s];
            }
            xs[wid][lane] = acc;
        }
        __syncthreads();
        if (n < n_nodes) {
            float o = bj * snorm[n];
            const float4* xr = (const float4*)xs[wid];
#pragma unroll
            for (int k4 = 0; k4 < 16; ++k4) {
                float4 xv = xr[k4];
                o += xv.x * w[4 * k4 + 0];
                o += xv.y * w[4 * k4 + 1];
                o += xv.z * w[4 * k4 + 2];
                o += xv.w * w[4 * k4 + 3];
            }
            o = fmaxf(o * norm[n], 0.f) + h_in[n * 64 + lane];
            h_out[n * 64 + lane] = o;
        }
        __syncthreads();
    }
}

// ---------------- fused A/B projection, bf16 output ----------------
// A = h @ M0[0:64], B = h @ M0[64:128]

__global__ __launch_bounds__(256) void k_matvec2(const float* __restrict__ h,
                                                 const float* __restrict__ Wa,
                                                 const float* __restrict__ Wb,
                                                 unsigned short* __restrict__ Ab,
                                                 unsigned short* __restrict__ Bb,
                                                 int n_nodes) {
    __shared__ float xs[4][64];
    const int lane = threadIdx.x & 63;
    const int wid  = threadIdx.x >> 6;
    float wa[64], wb[64];
#pragma unroll
    for (int k = 0; k < 64; ++k) wa[k] = Wa[k * 64 + lane];
#pragma unroll
    for (int k = 0; k < 64; ++k) wb[k] = Wb[k * 64 + lane];
    const int wg = blockIdx.x * 4 + wid;
    const int nw = gridDim.x * 4;
    const int niter = (n_nodes + nw - 1) / nw;
    for (int it = 0; it < niter; ++it) {
        const int n = wg + it * nw;
        if (n < n_nodes) xs[wid][lane] = h[n * 64 + lane];
        __syncthreads();
        if (n < n_nodes) {
            float oa = 0.f, ob = 0.f;
            const float4* xr = (const float4*)xs[wid];
#pragma unroll
            for (int k4 = 0; k4 < 16; ++k4) {
                float4 xv = xr[k4];
                oa += xv.x * wa[4 * k4 + 0]; ob += xv.x * wb[4 * k4 + 0];
                oa += xv.y * wa[4 * k4 + 1]; ob += xv.y * wb[4 * k4 + 1];
                oa += xv.z * wa[4 * k4 + 2]; ob += xv.z * wb[4 * k4 + 2];
                oa += xv.w * wa[4 * k4 + 3]; ob += xv.w * wb[4 * k4 + 3];
            }
            Ab[n * 64 + lane] = f2bf(oa);
            Bb[n * 64 + lane] = f2bf(ob);
        }
        __syncthreads();
    }
}

// ---------------- tiny embedding projections ----------------

__global__ void k_small(const float* __restrict__ curr_emb, const float* __restrict__ pay_emb,
                        const float* __restrict__ M0, float* __restrict__ C1,
                        float* __restrict__ C2, float* __restrict__ P) {
    int tid = threadIdx.x;
    for (int idx = tid; idx < 15 * 64; idx += blockDim.x) {
        int c = idx >> 6, j = idx & 63;
        float s1 = 0.f, s2 = 0.f;
        for (int k = 0; k < 8; ++k) {
            float ce = curr_emb[c * 8 + k];
            s1 += ce * M0[(128 + k) * 64 + j];
            s2 += ce * M0[(136 + k) * 64 + j];
        }
        C1[idx] = s1;
        C2[idx] = s2;
    }
    for (int idx = tid; idx < 7 * 64; idx += blockDim.x) {
        int p = idx >> 6, j = idx & 63;
        float s = 0.f;
        for (int k = 0; k < 4; ++k) s += pay_emb[p * 4 + k] * M0[(144 + k) * 64 + j];
        P[idx] = s;
    }
}

// ---------------- edge MLP ----------------

__global__ __launch_bounds__(256) void k_edge(const unsigned short* __restrict__ A,
                                              const unsigned short* __restrict__ B,
                                              const float* __restrict__ C1,
                                              const float* __restrict__ C2,
                                              const float* __restrict__ P,
                                              const float* __restrict__ M0,
                                              const float* __restrict__ bM0,
                                              const float* __restrict__ M1,
                                              const float* __restrict__ bM1,
                                              const float* __restrict__ M2,
                                              const float* __restrict__ bM2,
                                              const int* __restrict__ src,
                                              const int* __restrict__ dst,
                                              const int* __restrict__ pc,
                                              const int* __restrict__ rc,
                                              const int* __restrict__ pf,
                                              const float* __restrict__ num,
                                              float* __restrict__ out, int n_edges) {
    __shared__ float xs[4][64];
    const int lane = threadIdx.x & 63;
    const int wid  = threadIdx.x >> 6;
    float m1[64];
#pragma unroll
    for (int k = 0; k < 64; ++k) m1[k] = M1[k * 64 + lane];
    float m0n[5];
#pragma unroll
    for (int k = 0; k < 5; ++k) m0n[k] = M0[(148 + k) * 64 + lane];
    const float bm0 = bM0[lane], bm1 = bM1[lane];
    const float m2a = M2[lane * 2 + 0], m2b = M2[lane * 2 + 1];
    const float bm2a = bM2[0], bm2b = bM2[1];
    const int wg = blockIdx.x * 4 + wid;
    const int nw = gridDim.x * 4;
    const int niter = (n_edges + nw - 1) / nw;
    for (int it = 0; it < niter; ++it) {
        const int e = wg + it * nw;
        if (e < n_edges) {
            int s = src[e], d = dst[e];
            int c1 = pc[e], c2 = rc[e], p = pf[e];
            float x0 = bf2f(A[s * 64 + lane]) + bf2f(B[d * 64 + lane])
                     + C1[c1 * 64 + lane] + C2[c2 * 64 + lane] + P[p * 64 + lane] + bm0;
#pragma unroll
            for (int k = 0; k < 5; ++k) x0 += num[e * 5 + k] * m0n[k];
            xs[wid][lane] = fmaxf(x0, 0.f);
        }
        __syncthreads();
        if (e < n_edges) {
            float x1 = bm1;
            const float4* xr = (const float4*)xs[wid];
#pragma unroll
            for (int k4 = 0; k4 < 16; ++k4) {
                float4 xv = xr[k4];
                x1 += xv.x * m1[4 * k4 + 0];
                x1 += xv.y * m1[4 * k4 + 1];
                x1 += xv.z * m1[4 * k4 + 2];
                x1 += xv.w * m1[4 * k4 + 3];
            }
            x1 = fmaxf(x1, 0.f);
            float p0 = x1 * m2a, p1 = x1 * m2b;
#pragma unroll
            for (int off = 32; off; off >>= 1) {
                p0 += __shfl_xor(p0, off);
                p1 += __shfl_xor(p1, off);
            }
            if (lane == 0) ((float2*)out)[e] = make_float2(p0 + bm2a, p1 + bm2b);
        }
        __syncthreads();
    }
}

// ---------------- launch ----------------

extern "C" void kernel_launch(void* const* d_in, const int* in_sizes, int n_in,
                              void* d_out, int out_size, void* d_ws, size_t ws_size,
                              hipStream_t stream) {
    const float2* node_feats = (const float2*)d_in[0];
    const int*   src  = (const int*)d_in[1];
    const int*   dst  = (const int*)d_in[2];
    const int*   pc   = (const int*)d_in[3];
    const int*   rc   = (const int*)d_in[4];
    const int*   pf   = (const int*)d_in[5];
    const float* num  = (const float*)d_in[6];
    const float* W0   = (const float*)d_in[7];
    const float* b0   = (const float*)d_in[8];
    const float* W1   = (const float*)d_in[9];
    const float* b1   = (const float*)d_in[10];
    const float* W2   = (const float*)d_in[11];
    const float* b2   = (const float*)d_in[12];
    const float* curr_emb = (const float*)d_in[13];
    const float* pay_emb  = (const float*)d_in[14];
    const float* M0   = (const float*)d_in[15];
    const float* bM0  = (const float*)d_in[16];
    const float* M1   = (const float*)d_in[17];
    const float* bM1  = (const float*)d_in[18];
    const float* M2   = (const float*)d_in[19];
    const float* bM2  = (const float*)d_in[20];
    float* out = (float*)d_out;

    char* w = (char*)d_ws;
    auto alloc = [&](size_t bytes) {
        char* p = w;
        w += (bytes + 255) & ~size_t(255);
        return p;
    };
    int*    deg     = (int*)alloc(N_NODES * 4);
    float*  norm    = (float*)alloc(N_NODES * 4);
    float*  snorm   = (float*)alloc(N_NODES * 4);
    float2* aggnf   = (float2*)alloc(N_NODES * 8);
    int*    row_ptr = (int*)alloc((N_NODES + 1) * 4);
    int*    cursor  = (int*)alloc(N_NODES * 4);
    int*    csr_src = (int*)alloc(N_EDGES * 4);
    float*  buf0    = (float*)alloc(N_NODES * HID * 4);
    float*  buf1    = (float*)alloc(N_NODES * HID * 4);
    unsigned short* Ab = (unsigned short*)alloc(N_NODES * HID * 2);
    unsigned short* Bb = (unsigned short*)alloc(N_NODES * HID * 2);
    float*  C1      = (float*)alloc(15 * 64 * 4);
    float*  C2      = (float*)alloc(15 * 64 * 4);
    float*  P       = (float*)alloc(7 * 64 * 4);

    hipMemsetAsync(deg, 0, N_NODES * 4, stream);
    k_deg<<<(N_EDGES + 255) / 256, 256, 0, stream>>>(dst, deg, N_EDGES);
    k_norm<<<(N_NODES + 255) / 256, 256, 0, stream>>>(deg, norm, N_NODES);
    k_scan<<<1, 1024, 0, stream>>>(deg, row_ptr, cursor, N_NODES);
    k_scatter<<<(N_EDGES + 255) / 256, 256, 0, stream>>>(src, dst, cursor, csr_src, N_EDGES);
    k_aggnf<<<(N_NODES + 255) / 256, 256, 0, stream>>>(node_feats, norm, row_ptr, csr_src,
                                                       aggnf, snorm, N_NODES);
    k_h0<<<(N_NODES * HID + 255) / 256, 256, 0, stream>>>(aggnf, snorm, norm, W0, b0, buf0,
                                                          N_NODES * HID);
    k_layer<<<1536, 256, 0, stream>>>(buf0, buf1, W1, b1, norm, snorm, row_ptr, csr_src, N_NODES);
    k_layer<<<1536, 256, 0, stream>>>(buf1, buf0, W2, b2, norm, snorm, row_ptr, csr_src, N_NODES);
    k_small<<<1, 256, 0, stream>>>(curr_emb, pay_emb, M0, C1, C2, P);
    k_matvec2<<<1536, 256, 0, stream>>>(buf0, M0, M0 + 64 * 64, Ab, Bb, N_NODES);
    k_edge<<<1536, 256, 0, stream>>>(Ab, Bb, C1, C2, P, M0, bM0, M1, bM1, M2, bM2,
                                     src, dst, pc, rc, pf, num, out, N_EDGES);
}

// Round 3
// 737.648 us; speedup vs baseline: 1.3132x; 1.2443x over previous
//
#include <hip/hip_runtime.h>

#define N_NODES 50000
#define N_EDGES 800000
#define HID 64

__device__ __forceinline__ unsigned short f2bf(float f) {
    union { float f; unsigned int i; } v;
    v.f = f;
    unsigned int b = v.i;
    return (unsigned short)((b + 0x7FFFu + ((b >> 16) & 1u)) >> 16);
}

// add a 64-wide bf16 row into x[64]
__device__ __forceinline__ void add_bf16_row(float* x, const unsigned short* row) {
    const uint4* r4 = (const uint4*)row;
#pragma unroll
    for (int q = 0; q < 8; ++q) {
        uint4 v = r4[q];
        unsigned int u0 = v.x, u1 = v.y, u2 = v.z, u3 = v.w;
        union { unsigned int i; float f; } t;
        t.i = u0 << 16;         x[q*8 + 0] += t.f;
        t.i = u0 & 0xFFFF0000u; x[q*8 + 1] += t.f;
        t.i = u1 << 16;         x[q*8 + 2] += t.f;
        t.i = u1 & 0xFFFF0000u; x[q*8 + 3] += t.f;
        t.i = u2 << 16;         x[q*8 + 4] += t.f;
        t.i = u2 & 0xFFFF0000u; x[q*8 + 5] += t.f;
        t.i = u3 << 16;         x[q*8 + 6] += t.f;
        t.i = u3 & 0xFFFF0000u; x[q*8 + 7] += t.f;
    }
}

__device__ __forceinline__ void add_f32_row(float* x, const float* row) {
    const float4* r4 = (const float4*)row;
#pragma unroll
    for (int q = 0; q < 16; ++q) {
        float4 v = r4[q];
        x[q*4+0] += v.x; x[q*4+1] += v.y; x[q*4+2] += v.z; x[q*4+3] += v.w;
    }
}

// ---------------- CSR build ----------------

__global__ void k_deg(const int* __restrict__ dst, int* __restrict__ deg, int n) {
    int e = blockIdx.x * blockDim.x + threadIdx.x;
    if (e < n) atomicAdd(&deg[dst[e]], 1);
}

__global__ void k_norm(const int* __restrict__ deg, float* __restrict__ norm, int n) {
    int i = blockIdx.x * blockDim.x + threadIdx.x;
    if (i < n) {
        float d = (float)deg[i];
        norm[i] = 1.0f / sqrtf(fmaxf(d, 1.0f));
    }
}

// wave-scan offsets: row_ptr[i] = disjoint region start (order arbitrary)
__global__ void k_off(const int* __restrict__ deg, int* __restrict__ row_ptr,
                      int* __restrict__ cursor, int* __restrict__ gcount, int n) {
    int i = blockIdx.x * blockDim.x + threadIdx.x;
    int lane = threadIdx.x & 63;
    int v = (i < n) ? deg[i] : 0;
    int s = v;
#pragma unroll
    for (int off = 1; off < 64; off <<= 1) {
        int t = __shfl_up(s, off);
        if (lane >= off) s += t;
    }
    int total = __shfl(s, 63);
    int base = 0;
    if (lane == 63) base = atomicAdd(gcount, total);
    base = __shfl(base, 63);
    int ex = base + s - v;
    if (i < n) {
        row_ptr[i] = ex;
        cursor[i]  = ex;
    }
}

__global__ void k_scatter(const int* __restrict__ src, const int* __restrict__ dst,
                          int* __restrict__ cursor, int* __restrict__ csr_src, int n) {
    int e = blockIdx.x * blockDim.x + threadIdx.x;
    if (e < n) {
        int d = dst[e];
        int pos = atomicAdd(&cursor[d], 1);
        csr_src[pos] = src[e];
    }
}

// ---------------- GCN layer 0 (2-dim input, folded) ----------------

__global__ void k_aggnf(const float2* __restrict__ nf, const float* __restrict__ norm,
                        const int* __restrict__ row_ptr, const int* __restrict__ deg,
                        const int* __restrict__ csr_src,
                        float2* __restrict__ aggnf, float* __restrict__ snorm, int n_nodes) {
    int nd = blockIdx.x * blockDim.x + threadIdx.x;
    if (nd < n_nodes) {
        int r0 = row_ptr[nd], dc = deg[nd];
        float a0 = 0.f, a1 = 0.f, sn = 0.f;
        for (int i = 0; i < dc; ++i) {
            int s = csr_src[r0 + i];
            float ns = norm[s];
            float2 v = nf[s];
            a0 += v.x * ns;
            a1 += v.y * ns;
            sn += ns;
        }
        aggnf[nd] = make_float2(a0, a1);
        snorm[nd] = sn;
    }
}

__global__ void k_h0(const float2* __restrict__ aggnf, const float* __restrict__ snorm,
                     const float* __restrict__ norm, const float* __restrict__ W0,
                     const float* __restrict__ b0, float* __restrict__ h, int total) {
    int idx = blockIdx.x * blockDim.x + threadIdx.x;
    if (idx < total) {
        int n = idx >> 6, j = idx & 63;
        float2 a = aggnf[n];
        float v = (a.x * W0[j] + a.y * W0[64 + j] + b0[j] * snorm[n]) * norm[n];
        h[idx] = fmaxf(v, 0.f);
    }
}

// ---------------- GCN layers 1/2 — thread-per-node ----------------
// out = relu(((sum h[src]*norm[src]) @ W + b*snorm) * norm) + h_in

__global__ __launch_bounds__(256, 2) void k_layer(const float* __restrict__ h_in,
                                                  float* __restrict__ h_out,
                                                  const float* __restrict__ W,
                                                  const float* __restrict__ b,
                                                  const float* __restrict__ norm,
                                                  const float* __restrict__ snorm,
                                                  const int* __restrict__ row_ptr,
                                                  const int* __restrict__ deg,
                                                  const int* __restrict__ csr_src,
                                                  int n_nodes) {
    int n = blockIdx.x * blockDim.x + threadIdx.x;
    if (n >= n_nodes) return;
    int r0 = row_ptr[n], dc = deg[n];
    float x[64];
#pragma unroll
    for (int q = 0; q < 64; ++q) x[q] = 0.f;
    for (int i = 0; i < dc; ++i) {
        int s = csr_src[r0 + i];
        float ns = norm[s];
        const float4* hr = (const float4*)(h_in + (size_t)s * 64);
#pragma unroll
        for (int q = 0; q < 16; ++q) {
            float4 v = hr[q];
            x[q*4+0] = fmaf(ns, v.x, x[q*4+0]);
            x[q*4+1] = fmaf(ns, v.y, x[q*4+1]);
            x[q*4+2] = fmaf(ns, v.z, x[q*4+2]);
            x[q*4+3] = fmaf(ns, v.w, x[q*4+3]);
        }
    }
    float nn = norm[n], sn = snorm[n];
    const float* hme = h_in + (size_t)n * 64;
#pragma unroll
    for (int jh = 0; jh < 2; ++jh) {
        float y[32];
        const float4* b4 = (const float4*)(b + jh * 32);
#pragma unroll
        for (int q = 0; q < 8; ++q) {
            float4 v = b4[q];
            y[q*4+0] = v.x * sn; y[q*4+1] = v.y * sn;
            y[q*4+2] = v.z * sn; y[q*4+3] = v.w * sn;
        }
#pragma unroll
        for (int k = 0; k < 64; ++k) {
            float xk = x[k];
            const float4* m4 = (const float4*)(W + k * 64 + jh * 32);
#pragma unroll
            for (int q = 0; q < 8; ++q) {
                float4 v = m4[q];
                y[q*4+0] = fmaf(xk, v.x, y[q*4+0]);
                y[q*4+1] = fmaf(xk, v.y, y[q*4+1]);
                y[q*4+2] = fmaf(xk, v.z, y[q*4+2]);
                y[q*4+3] = fmaf(xk, v.w, y[q*4+3]);
            }
        }
        const float4* h4 = (const float4*)(hme + jh * 32);
        float4* o4 = (float4*)(h_out + (size_t)n * 64 + jh * 32);
#pragma unroll
        for (int q = 0; q < 8; ++q) {
            float4 hv = h4[q];
            float4 ov;
            ov.x = fmaxf(y[q*4+0] * nn, 0.f) + hv.x;
            ov.y = fmaxf(y[q*4+1] * nn, 0.f) + hv.y;
            ov.z = fmaxf(y[q*4+2] * nn, 0.f) + hv.z;
            ov.w = fmaxf(y[q*4+3] * nn, 0.f) + hv.w;
            o4[q] = ov;
        }
    }
}

// ---------------- A/B projection (thread-per-node), bf16 out ----------------

__global__ __launch_bounds__(256, 2) void k_matvec2(const float* __restrict__ h,
                                                    const float* __restrict__ M0,
                                                    unsigned short* __restrict__ Ab,
                                                    unsigned short* __restrict__ Bb,
                                                    int n_nodes) {
    int n = blockIdx.x * blockDim.x + threadIdx.x;
    if (n >= n_nodes) return;
    float x[64];
    const float4* hr = (const float4*)(h + (size_t)n * 64);
#pragma unroll
    for (int q = 0; q < 16; ++q) {
        float4 v = hr[q];
        x[q*4+0] = v.x; x[q*4+1] = v.y; x[q*4+2] = v.z; x[q*4+3] = v.w;
    }
#pragma unroll
    for (int tbl = 0; tbl < 2; ++tbl) {
        const float* Wt = M0 + tbl * 4096;
        unsigned short* Ot = tbl ? Bb : Ab;
#pragma unroll
        for (int jh = 0; jh < 2; ++jh) {
            float y[32];
#pragma unroll
            for (int q = 0; q < 32; ++q) y[q] = 0.f;
#pragma unroll
            for (int k = 0; k < 64; ++k) {
                float xk = x[k];
                const float4* m4 = (const float4*)(Wt + k * 64 + jh * 32);
#pragma unroll
                for (int q = 0; q < 8; ++q) {
                    float4 v = m4[q];
                    y[q*4+0] = fmaf(xk, v.x, y[q*4+0]);
                    y[q*4+1] = fmaf(xk, v.y, y[q*4+1]);
                    y[q*4+2] = fmaf(xk, v.z, y[q*4+2]);
                    y[q*4+3] = fmaf(xk, v.w, y[q*4+3]);
                }
            }
            uint4* o4 = (uint4*)(Ot + (size_t)n * 64 + jh * 32);
#pragma unroll
            for (int q = 0; q < 4; ++q) {
                uint4 ov;
                ov.x = (unsigned int)f2bf(y[q*8+0]) | ((unsigned int)f2bf(y[q*8+1]) << 16);
                ov.y = (unsigned int)f2bf(y[q*8+2]) | ((unsigned int)f2bf(y[q*8+3]) << 16);
                ov.z = (unsigned int)f2bf(y[q*8+4]) | ((unsigned int)f2bf(y[q*8+5]) << 16);
                ov.w = (unsigned int)f2bf(y[q*8+6]) | ((unsigned int)f2bf(y[q*8+7]) << 16);
                o4[q] = ov;
            }
        }
    }
}

// ---------------- tiny embedding projections ----------------

__global__ void k_small(const float* __restrict__ curr_emb, const float* __restrict__ pay_emb,
                        const float* __restrict__ M0, float* __restrict__ C1,
                        float* __restrict__ C2, float* __restrict__ P) {
    int tid = threadIdx.x;
    for (int idx = tid; idx < 15 * 64; idx += blockDim.x) {
        int c = idx >> 6, j = idx & 63;
        float s1 = 0.f, s2 = 0.f;
        for (int k = 0; k < 8; ++k) {
            float ce = curr_emb[c * 8 + k];
            s1 += ce * M0[(128 + k) * 64 + j];
            s2 += ce * M0[(136 + k) * 64 + j];
        }
        C1[idx] = s1;
        C2[idx] = s2;
    }
    for (int idx = tid; idx < 7 * 64; idx += blockDim.x) {
        int p = idx >> 6, j = idx & 63;
        float s = 0.f;
        for (int k = 0; k < 4; ++k) s += pay_emb[p * 4 + k] * M0[(144 + k) * 64 + j];
        P[idx] = s;
    }
}

// ---------------- edge MLP — thread-per-edge ----------------

__global__ __launch_bounds__(256, 2) void k_edge(const unsigned short* __restrict__ Ab,
                                                 const unsigned short* __restrict__ Bb,
                                                 const float* __restrict__ C1,
                                                 const float* __restrict__ C2,
                                                 const float* __restrict__ P,
                                                 const float* __restrict__ M0,
                                                 const float* __restrict__ bM0,
                                                 const float* __restrict__ M1,
                                                 const float* __restrict__ bM1,
                                                 const float* __restrict__ M2,
                                                 const float* __restrict__ bM2,
                                                 const int* __restrict__ src,
                                                 const int* __restrict__ dst,
                                                 const int* __restrict__ pc,
                                                 const int* __restrict__ rc,
                                                 const int* __restrict__ pf,
                                                 const float* __restrict__ num,
                                                 float* __restrict__ out, int n_edges) {
    int e = blockIdx.x * blockDim.x + threadIdx.x;
    if (e >= n_edges) return;
    int s = src[e], d = dst[e];
    int c1 = pc[e], c2 = rc[e], p = pf[e];
    float nk[5];
#pragma unroll
    for (int k = 0; k < 5; ++k) nk[k] = num[(size_t)e * 5 + k];

    float x0[64];
    const float4* b4 = (const float4*)bM0;
#pragma unroll
    for (int q = 0; q < 16; ++q) {
        float4 v = b4[q];
        x0[q*4+0] = v.x; x0[q*4+1] = v.y; x0[q*4+2] = v.z; x0[q*4+3] = v.w;
    }
    add_bf16_row(x0, Ab + (size_t)s * 64);
    add_bf16_row(x0, Bb + (size_t)d * 64);
    add_f32_row(x0, C1 + c1 * 64);
    add_f32_row(x0, C2 + c2 * 64);
    add_f32_row(x0, P + p * 64);
#pragma unroll
    for (int k = 0; k < 5; ++k) {
        const float4* m4 = (const float4*)(M0 + (148 + k) * 64);
        float nkk = nk[k];
#pragma unroll
        for (int q = 0; q < 16; ++q) {
            float4 v = m4[q];
            x0[q*4+0] = fmaf(nkk, v.x, x0[q*4+0]);
            x0[q*4+1] = fmaf(nkk, v.y, x0[q*4+1]);
            x0[q*4+2] = fmaf(nkk, v.z, x0[q*4+2]);
            x0[q*4+3] = fmaf(nkk, v.w, x0[q*4+3]);
        }
    }
#pragma unroll
    for (int k = 0; k < 64; ++k) x0[k] = fmaxf(x0[k], 0.f);

    float lg0 = bM2[0], lg1 = bM2[1];
#pragma unroll
    for (int jh = 0; jh < 2; ++jh) {
        float x1[32];
        const float4* bb = (const float4*)(bM1 + jh * 32);
#pragma unroll
        for (int q = 0; q < 8; ++q) {
            float4 v = bb[q];
            x1[q*4+0] = v.x; x1[q*4+1] = v.y; x1[q*4+2] = v.z; x1[q*4+3] = v.w;
        }
#pragma unroll
        for (int k = 0; k < 64; ++k) {
            float xk = x0[k];
            const float4* m4 = (const float4*)(M1 + k * 64 + jh * 32);
#pragma unroll
            for (int q = 0; q < 8; ++q) {
                float4 v = m4[q];
                x1[q*4+0] = fmaf(xk, v.x, x1[q*4+0]);
                x1[q*4+1] = fmaf(xk, v.y, x1[q*4+1]);
                x1[q*4+2] = fmaf(xk, v.z, x1[q*4+2]);
                x1[q*4+3] = fmaf(xk, v.w, x1[q*4+3]);
            }
        }
#pragma unroll
        for (int j = 0; j < 32; ++j) {
            float xv = fmaxf(x1[j], 0.f);
            int jj = jh * 32 + j;
            lg0 = fmaf(xv, M2[jj * 2 + 0], lg0);
            lg1 = fmaf(xv, M2[jj * 2 + 1], lg1);
        }
    }
    ((float2*)out)[e] = make_float2(lg0, lg1);
}

// ---------------- launch ----------------

extern "C" void kernel_launch(void* const* d_in, const int* in_sizes, int n_in,
                              void* d_out, int out_size, void* d_ws, size_t ws_size,
                              hipStream_t stream) {
    const float2* node_feats = (const float2*)d_in[0];
    const int*   src  = (const int*)d_in[1];
    const int*   dst  = (const int*)d_in[2];
    const int*   pc   = (const int*)d_in[3];
    const int*   rc   = (const int*)d_in[4];
    const int*   pf   = (const int*)d_in[5];
    const float* num  = (const float*)d_in[6];
    const float* W0   = (const float*)d_in[7];
    const float* b0   = (const float*)d_in[8];
    const float* W1   = (const float*)d_in[9];
    const float* b1   = (const float*)d_in[10];
    const float* W2   = (const float*)d_in[11];
    const float* b2   = (const float*)d_in[12];
    const float* curr_emb = (const float*)d_in[13];
    const float* pay_emb  = (const float*)d_in[14];
    const float* M0   = (const float*)d_in[15];
    const float* bM0  = (const float*)d_in[16];
    const float* M1   = (const float*)d_in[17];
    const float* bM1  = (const float*)d_in[18];
    const float* M2   = (const float*)d_in[19];
    const float* bM2  = (const float*)d_in[20];
    float* out = (float*)d_out;

    char* w = (char*)d_ws;
    auto alloc = [&](size_t bytes) {
        char* p = w;
        w += (bytes + 255) & ~size_t(255);
        return p;
    };
    int*    deg     = (int*)alloc(N_NODES * 4);
    int*    gcount  = (int*)alloc(256);
    float*  norm    = (float*)alloc(N_NODES * 4);
    float*  snorm   = (float*)alloc(N_NODES * 4);
    float2* aggnf   = (float2*)alloc(N_NODES * 8);
    int*    row_ptr = (int*)alloc((N_NODES + 1) * 4);
    int*    cursor  = (int*)alloc(N_NODES * 4);
    int*    csr_src = (int*)alloc(N_EDGES * 4);
    float*  buf0    = (float*)alloc(N_NODES * HID * 4);
    float*  buf1    = (float*)alloc(N_NODES * HID * 4);
    unsigned short* Ab = (unsigned short*)alloc(N_NODES * HID * 2);
    unsigned short* Bb = (unsigned short*)alloc(N_NODES * HID * 2);
    float*  C1      = (float*)alloc(15 * 64 * 4);
    float*  C2      = (float*)alloc(15 * 64 * 4);
    float*  P       = (float*)alloc(7 * 64 * 4);

    hipMemsetAsync(deg, 0, N_NODES * 4, stream);
    hipMemsetAsync(gcount, 0, 256, stream);
    k_deg<<<(N_EDGES + 255) / 256, 256, 0, stream>>>(dst, deg, N_EDGES);
    k_norm<<<(N_NODES + 255) / 256, 256, 0, stream>>>(deg, norm, N_NODES);
    k_off<<<(N_NODES + 255) / 256, 256, 0, stream>>>(deg, row_ptr, cursor, gcount, N_NODES);
    k_scatter<<<(N_EDGES + 255) / 256, 256, 0, stream>>>(src, dst, cursor, csr_src, N_EDGES);
    k_aggnf<<<(N_NODES + 255) / 256, 256, 0, stream>>>(node_feats, norm, row_ptr, deg, csr_src,
                                                       aggnf, snorm, N_NODES);
    k_h0<<<(N_NODES * HID + 255) / 256, 256, 0, stream>>>(aggnf, snorm, norm, W0, b0, buf0,
                                                          N_NODES * HID);
    k_layer<<<(N_NODES + 255) / 256, 256, 0, stream>>>(buf0, buf1, W1, b1, norm, snorm,
                                                       row_ptr, deg, csr_src, N_NODES);
    k_layer<<<(N_NODES + 255) / 256, 256, 0, stream>>>(buf1, buf0, W2, b2, norm, snorm,
                                                       row_ptr, deg, csr_src, N_NODES);
    k_small<<<1, 256, 0, stream>>>(curr_emb, pay_emb, M0, C1, C2, P);
    k_matvec2<<<(N_NODES + 255) / 256, 256, 0, stream>>>(buf0, M0, Ab, Bb, N_NODES);
    k_edge<<<(N_EDGES + 255) / 256, 256, 0, stream>>>(Ab, Bb, C1, C2, P, M0, bM0, M1, bM1,
                                                      M2, bM2, src, dst, pc, rc, pf, num,
                                                      out, N_EDGES);
}

// Round 4
// 621.601 us; speedup vs baseline: 1.5583x; 1.1867x over previous
//
#include <hip/hip_runtime.h>

#define N_NODES 50000
#define N_EDGES 800000
#define HID 64

__device__ __forceinline__ unsigned short f2bf(float f) {
    union { float f; unsigned int i; } v;
    v.f = f;
    unsigned int b = v.i;
    return (unsigned short)((b + 0x7FFFu + ((b >> 16) & 1u)) >> 16);
}

// add a 64-wide bf16 row into x[64]
__device__ __forceinline__ void add_bf16_row(float* x, const unsigned short* row) {
    const uint4* r4 = (const uint4*)row;
#pragma unroll
    for (int q = 0; q < 8; ++q) {
        uint4 v = r4[q];
        union { unsigned int i; float f; } t;
        t.i = v.x << 16;         x[q*8 + 0] += t.f;
        t.i = v.x & 0xFFFF0000u; x[q*8 + 1] += t.f;
        t.i = v.y << 16;         x[q*8 + 2] += t.f;
        t.i = v.y & 0xFFFF0000u; x[q*8 + 3] += t.f;
        t.i = v.z << 16;         x[q*8 + 4] += t.f;
        t.i = v.z & 0xFFFF0000u; x[q*8 + 5] += t.f;
        t.i = v.w << 16;         x[q*8 + 6] += t.f;
        t.i = v.w & 0xFFFF0000u; x[q*8 + 7] += t.f;
    }
}

// ---------------- CSR build ----------------

__global__ void k_deg(const int* __restrict__ dst, int* __restrict__ deg, int n) {
    int e = blockIdx.x * blockDim.x + threadIdx.x;
    if (e < n) atomicAdd(&deg[dst[e]], 1);
}

__global__ void k_norm(const int* __restrict__ deg, float* __restrict__ norm, int n) {
    int i = blockIdx.x * blockDim.x + threadIdx.x;
    if (i < n) {
        float d = (float)deg[i];
        norm[i] = 1.0f / sqrtf(fmaxf(d, 1.0f));
    }
}

// wave-scan offsets: row_ptr[i] = disjoint region start (order arbitrary)
__global__ void k_off(const int* __restrict__ deg, int* __restrict__ row_ptr,
                      int* __restrict__ cursor, int* __restrict__ gcount, int n) {
    int i = blockIdx.x * blockDim.x + threadIdx.x;
    int lane = threadIdx.x & 63;
    int v = (i < n) ? deg[i] : 0;
    int s = v;
#pragma unroll
    for (int off = 1; off < 64; off <<= 1) {
        int t = __shfl_up(s, off);
        if (lane >= off) s += t;
    }
    int total = __shfl(s, 63);
    int base = 0;
    if (lane == 63) base = atomicAdd(gcount, total);
    base = __shfl(base, 63);
    int ex = base + s - v;
    if (i < n) {
        row_ptr[i] = ex;
        cursor[i]  = ex;
    }
}

__global__ void k_scatter(const int* __restrict__ src, const int* __restrict__ dst,
                          int* __restrict__ cursor, int* __restrict__ csr_src, int n) {
    int e = blockIdx.x * blockDim.x + threadIdx.x;
    if (e < n) {
        int d = dst[e];
        int pos = atomicAdd(&cursor[d], 1);
        csr_src[pos] = src[e];
    }
}

// ---------------- layer-0 aggregation: wave per node, lane-parallel edges ----------------

__global__ __launch_bounds__(256) void k_aggnf(const float2* __restrict__ nf,
                                               const float* __restrict__ norm,
                                               const int* __restrict__ row_ptr,
                                               const int* __restrict__ deg,
                                               const int* __restrict__ csr_src,
                                               float2* __restrict__ aggnf,
                                               float* __restrict__ snorm, int n_nodes) {
    int lane = threadIdx.x & 63, wid = threadIdx.x >> 6;
    int n = blockIdx.x * 4 + wid;
    if (n >= n_nodes) return;
    int r0 = row_ptr[n], dc = deg[n];
    float a0 = 0.f, a1 = 0.f, sn = 0.f;
    for (int i = lane; i < dc; i += 64) {
        int s = csr_src[r0 + i];
        float ns = norm[s];
        float2 v = nf[s];
        a0 += v.x * ns;
        a1 += v.y * ns;
        sn += ns;
    }
#pragma unroll
    for (int off = 32; off; off >>= 1) {
        a0 += __shfl_xor(a0, off);
        a1 += __shfl_xor(a1, off);
        sn += __shfl_xor(sn, off);
    }
    if (lane == 0) {
        aggnf[n] = make_float2(a0, a1);
        snorm[n] = sn;
    }
}

// h0 = relu((aggnf @ W0 + b0*snorm) * norm); also h0n = h0 * norm
__global__ void k_h0(const float2* __restrict__ aggnf, const float* __restrict__ snorm,
                     const float* __restrict__ norm, const float* __restrict__ W0,
                     const float* __restrict__ b0, float* __restrict__ h,
                     float* __restrict__ hn, int total) {
    int idx = blockIdx.x * blockDim.x + threadIdx.x;
    if (idx < total) {
        int n = idx >> 6, j = idx & 63;
        float2 a = aggnf[n];
        float nnv = norm[n];
        float v = (a.x * W0[j] + a.y * W0[64 + j] + b0[j] * snorm[n]) * nnv;
        v = fmaxf(v, 0.f);
        h[idx] = v;
        hn[idx] = v * nnv;
    }
}

// ---------------- aggregation: g[n] = sum_{s in N(n)} hn[s]  (hn pre-scaled) ----------------

__global__ __launch_bounds__(256) void k_agg(const float* __restrict__ hn,
                                             const int* __restrict__ row_ptr,
                                             const int* __restrict__ deg,
                                             const int* __restrict__ csr_src,
                                             float* __restrict__ g, int n_nodes) {
    int lane = threadIdx.x & 63, wid = threadIdx.x >> 6;
    int n = blockIdx.x * 4 + wid;
    if (n >= n_nodes) return;
    int r0 = row_ptr[n], dc = deg[n];
    float acc = 0.f;
    int i = 0;
    for (; i + 4 <= dc; i += 4) {
        int s0 = csr_src[r0 + i + 0];
        int s1 = csr_src[r0 + i + 1];
        int s2 = csr_src[r0 + i + 2];
        int s3 = csr_src[r0 + i + 3];
        float v0 = hn[(size_t)s0 * 64 + lane];
        float v1 = hn[(size_t)s1 * 64 + lane];
        float v2 = hn[(size_t)s2 * 64 + lane];
        float v3 = hn[(size_t)s3 * 64 + lane];
        acc += (v0 + v1) + (v2 + v3);
    }
    for (; i < dc; ++i) acc += hn[(size_t)csr_src[r0 + i] * 64 + lane];
    g[(size_t)n * 64 + lane] = acc;
}

// ---------------- dense: h_out = relu((g@W + b*snorm)*norm) + h_in; hn_out optional ----------------
// block = 64-node tile; wave wid computes outputs [wid*16, wid*16+16) -> weights wave-uniform (s_load)

__global__ __launch_bounds__(256) void k_mv(const float* __restrict__ g,
                                            const float* __restrict__ h_in,
                                            const float* __restrict__ W,
                                            const float* __restrict__ b,
                                            const float* __restrict__ norm,
                                            const float* __restrict__ snorm,
                                            float* __restrict__ h_out,
                                            float* __restrict__ hn_out, int n_nodes) {
    int lane = threadIdx.x & 63, wid = threadIdx.x >> 6;
    int n = blockIdx.x * 64 + lane;
    if (n >= n_nodes) return;
    const int j0 = wid * 16;
    float sn = snorm[n];
    float y[16];
    const float* bj = b + j0;
#pragma unroll
    for (int q = 0; q < 16; ++q) y[q] = bj[q] * sn;
    const float4* g4 = (const float4*)(g + (size_t)n * 64);
    const float* Wj = W + j0;
#pragma unroll
    for (int k4 = 0; k4 < 16; ++k4) {
        float4 xv = g4[k4];
        const float* w0 = Wj + (k4 * 4 + 0) * 64;
        const float* w1 = Wj + (k4 * 4 + 1) * 64;
        const float* w2 = Wj + (k4 * 4 + 2) * 64;
        const float* w3 = Wj + (k4 * 4 + 3) * 64;
#pragma unroll
        for (int q = 0; q < 16; ++q) {
            y[q] = fmaf(xv.x, w0[q], y[q]);
            y[q] = fmaf(xv.y, w1[q], y[q]);
            y[q] = fmaf(xv.z, w2[q], y[q]);
            y[q] = fmaf(xv.w, w3[q], y[q]);
        }
    }
    float nn = norm[n];
    const float4* h4 = (const float4*)(h_in + (size_t)n * 64 + j0);
    float4* o4 = (float4*)(h_out + (size_t)n * 64 + j0);
#pragma unroll
    for (int q4 = 0; q4 < 4; ++q4) {
        float4 hv = h4[q4];
        float4 ov;
        ov.x = fmaxf(y[q4*4+0] * nn, 0.f) + hv.x;
        ov.y = fmaxf(y[q4*4+1] * nn, 0.f) + hv.y;
        ov.z = fmaxf(y[q4*4+2] * nn, 0.f) + hv.z;
        ov.w = fmaxf(y[q4*4+3] * nn, 0.f) + hv.w;
        o4[q4] = ov;
    }
    if (hn_out) {
        float4* s4 = (float4*)(hn_out + (size_t)n * 64 + j0);
#pragma unroll
        for (int q4 = 0; q4 < 4; ++q4) {
            float4 ov = o4[q4];
            float4 sv;
            sv.x = ov.x * nn; sv.y = ov.y * nn; sv.z = ov.z * nn; sv.w = ov.w * nn;
            s4[q4] = sv;
        }
    }
}

// ---------------- A/B projection: block 512 = 8 waves; wid>>2 -> table, wid&3 -> 16-col group ----

__global__ __launch_bounds__(512) void k_mv2(const float* __restrict__ h,
                                             const float* __restrict__ M0,
                                             unsigned short* __restrict__ Ab,
                                             unsigned short* __restrict__ Bb,
                                             int n_nodes) {
    int lane = threadIdx.x & 63, wid = threadIdx.x >> 6;
    int n = blockIdx.x * 64 + lane;
    if (n >= n_nodes) return;
    const int tbl = wid >> 2;
    const int j0 = (wid & 3) * 16;
    float y[16];
#pragma unroll
    for (int q = 0; q < 16; ++q) y[q] = 0.f;
    const float4* h4 = (const float4*)(h + (size_t)n * 64);
    const float* Wj = M0 + tbl * 4096 + j0;
#pragma unroll
    for (int k4 = 0; k4 < 16; ++k4) {
        float4 xv = h4[k4];
        const float* w0 = Wj + (k4 * 4 + 0) * 64;
        const float* w1 = Wj + (k4 * 4 + 1) * 64;
        const float* w2 = Wj + (k4 * 4 + 2) * 64;
        const float* w3 = Wj + (k4 * 4 + 3) * 64;
#pragma unroll
        for (int q = 0; q < 16; ++q) {
            y[q] = fmaf(xv.x, w0[q], y[q]);
            y[q] = fmaf(xv.y, w1[q], y[q]);
            y[q] = fmaf(xv.z, w2[q], y[q]);
            y[q] = fmaf(xv.w, w3[q], y[q]);
        }
    }
    unsigned short* Ot = (tbl ? Bb : Ab) + (size_t)n * 64 + j0;
    uint4* o4 = (uint4*)Ot;
#pragma unroll
    for (int q = 0; q < 2; ++q) {
        uint4 ov;
        ov.x = (unsigned int)f2bf(y[q*8+0]) | ((unsigned int)f2bf(y[q*8+1]) << 16);
        ov.y = (unsigned int)f2bf(y[q*8+2]) | ((unsigned int)f2bf(y[q*8+3]) << 16);
        ov.z = (unsigned int)f2bf(y[q*8+4]) | ((unsigned int)f2bf(y[q*8+5]) << 16);
        ov.w = (unsigned int)f2bf(y[q*8+6]) | ((unsigned int)f2bf(y[q*8+7]) << 16);
        o4[q] = ov;
    }
}

// ---------------- tiny embedding projections + combo table ----------------

__global__ void k_small(const float* __restrict__ curr_emb, const float* __restrict__ pay_emb,
                        const float* __restrict__ M0, float* __restrict__ C1,
                        float* __restrict__ C2, float* __restrict__ P) {
    int tid = threadIdx.x;
    for (int idx = tid; idx < 15 * 64; idx += blockDim.x) {
        int c = idx >> 6, j = idx & 63;
        float s1 = 0.f, s2 = 0.f;
        for (int k = 0; k < 8; ++k) {
            float ce = curr_emb[c * 8 + k];
            s1 += ce * M0[(128 + k) * 64 + j];
            s2 += ce * M0[(136 + k) * 64 + j];
        }
        C1[idx] = s1;
        C2[idx] = s2;
    }
    for (int idx = tid; idx < 7 * 64; idx += blockDim.x) {
        int p = idx >> 6, j = idx & 63;
        float s = 0.f;
        for (int k = 0; k < 4; ++k) s += pay_emb[p * 4 + k] * M0[(144 + k) * 64 + j];
        P[idx] = s;
    }
}

// T[(c1*15+c2)*7+p][j] = C1[c1][j] + C2[c2][j] + P[p][j] + bM0[j]
__global__ void k_combo(const float* __restrict__ C1, const float* __restrict__ C2,
                        const float* __restrict__ P, const float* __restrict__ bM0,
                        float* __restrict__ T, int total) {
    int idx = blockIdx.x * blockDim.x + threadIdx.x;
    if (idx < total) {
        int j = idx & 63, c = idx >> 6;
        int p = c % 7, cc = c / 7;
        int c2 = cc % 15, c1 = cc / 15;
        T[idx] = C1[c1 * 64 + j] + C2[c2 * 64 + j] + P[p * 64 + j] + bM0[j];
    }
}

// ---------------- edge MLP — thread-per-edge ----------------

__global__ __launch_bounds__(256, 2) void k_edge(const unsigned short* __restrict__ Ab,
                                                 const unsigned short* __restrict__ Bb,
                                                 const float* __restrict__ T,
                                                 const float* __restrict__ M0,
                                                 const float* __restrict__ M1,
                                                 const float* __restrict__ bM1,
                                                 const float* __restrict__ M2,
                                                 const float* __restrict__ bM2,
                                                 const int* __restrict__ src,
                                                 const int* __restrict__ dst,
                                                 const int* __restrict__ pc,
                                                 const int* __restrict__ rc,
                                                 const int* __restrict__ pf,
                                                 const float* __restrict__ num,
                                                 float* __restrict__ out, int n_edges) {
    int e = blockIdx.x * blockDim.x + threadIdx.x;
    if (e >= n_edges) return;
    int s = src[e], d = dst[e];
    int combo = (pc[e] * 15 + rc[e]) * 7 + pf[e];
    float nk[5];
#pragma unroll
    for (int k = 0; k < 5; ++k) nk[k] = num[(size_t)e * 5 + k];

    float x0[64];
    const float4* t4 = (const float4*)(T + (size_t)combo * 64);
#pragma unroll
    for (int q = 0; q < 16; ++q) {
        float4 v = t4[q];
        x0[q*4+0] = v.x; x0[q*4+1] = v.y; x0[q*4+2] = v.z; x0[q*4+3] = v.w;
    }
    add_bf16_row(x0, Ab + (size_t)s * 64);
    add_bf16_row(x0, Bb + (size_t)d * 64);
#pragma unroll
    for (int k = 0; k < 5; ++k) {
        const float* m4 = M0 + (148 + k) * 64;
        float nkk = nk[k];
#pragma unroll
        for (int q = 0; q < 64; ++q) x0[q] = fmaf(nkk, m4[q], x0[q]);
    }
#pragma unroll
    for (int k = 0; k < 64; ++k) x0[k] = fmaxf(x0[k], 0.f);

    float lg0 = bM2[0], lg1 = bM2[1];
#pragma unroll
    for (int jh = 0; jh < 2; ++jh) {
        float x1[32];
        const float* bb = bM1 + jh * 32;
#pragma unroll
        for (int q = 0; q < 32; ++q) x1[q] = bb[q];
#pragma unroll
        for (int k = 0; k < 64; ++k) {
            float xk = x0[k];
            const float* mr = M1 + k * 64 + jh * 32;
#pragma unroll
            for (int q = 0; q < 32; ++q) x1[q] = fmaf(xk, mr[q], x1[q]);
        }
#pragma unroll
        for (int j = 0; j < 32; ++j) {
            float xv = fmaxf(x1[j], 0.f);
            int jj = jh * 32 + j;
            lg0 = fmaf(xv, M2[jj * 2 + 0], lg0);
            lg1 = fmaf(xv, M2[jj * 2 + 1], lg1);
        }
    }
    ((float2*)out)[e] = make_float2(lg0, lg1);
}

// ---------------- launch ----------------

extern "C" void kernel_launch(void* const* d_in, const int* in_sizes, int n_in,
                              void* d_out, int out_size, void* d_ws, size_t ws_size,
                              hipStream_t stream) {
    const float2* node_feats = (const float2*)d_in[0];
    const int*   src  = (const int*)d_in[1];
    const int*   dst  = (const int*)d_in[2];
    const int*   pc   = (const int*)d_in[3];
    const int*   rc   = (const int*)d_in[4];
    const int*   pf   = (const int*)d_in[5];
    const float* num  = (const float*)d_in[6];
    const float* W0   = (const float*)d_in[7];
    const float* b0   = (const float*)d_in[8];
    const float* W1   = (const float*)d_in[9];
    const float* b1   = (const float*)d_in[10];
    const float* W2   = (const float*)d_in[11];
    const float* b2   = (const float*)d_in[12];
    const float* curr_emb = (const float*)d_in[13];
    const float* pay_emb  = (const float*)d_in[14];
    const float* M0   = (const float*)d_in[15];
    const float* bM0  = (const float*)d_in[16];
    const float* M1   = (const float*)d_in[17];
    const float* bM1  = (const float*)d_in[18];
    const float* M2   = (const float*)d_in[19];
    const float* bM2  = (const float*)d_in[20];
    float* out = (float*)d_out;

    char* w = (char*)d_ws;
    auto alloc = [&](size_t bytes) {
        char* p = w;
        w += (bytes + 255) & ~size_t(255);
        return p;
    };
    int*    deg     = (int*)alloc(N_NODES * 4);
    int*    gcount  = (int*)alloc(256);
    float*  norm    = (float*)alloc(N_NODES * 4);
    float*  snorm   = (float*)alloc(N_NODES * 4);
    float2* aggnf   = (float2*)alloc(N_NODES * 8);
    int*    row_ptr = (int*)alloc((N_NODES + 1) * 4);
    int*    cursor  = (int*)alloc(N_NODES * 4);
    int*    csr_src = (int*)alloc(N_EDGES * 4);
    float*  B1      = (float*)alloc(N_NODES * HID * 4);   // h0 -> h2
    float*  B2      = (float*)alloc(N_NODES * HID * 4);   // h0n -> h1n
    float*  B3      = (float*)alloc(N_NODES * HID * 4);   // g
    float*  B4      = (float*)alloc(N_NODES * HID * 4);   // h1
    unsigned short* Ab = (unsigned short*)alloc(N_NODES * HID * 2);
    unsigned short* Bb = (unsigned short*)alloc(N_NODES * HID * 2);
    float*  C1      = (float*)alloc(15 * 64 * 4);
    float*  C2      = (float*)alloc(15 * 64 * 4);
    float*  P       = (float*)alloc(7 * 64 * 4);
    float*  T       = (float*)alloc(15 * 15 * 7 * 64 * 4);

    hipMemsetAsync(deg, 0, N_NODES * 4, stream);
    hipMemsetAsync(gcount, 0, 256, stream);
    k_deg<<<(N_EDGES + 255) / 256, 256, 0, stream>>>(dst, deg, N_EDGES);
    k_norm<<<(N_NODES + 255) / 256, 256, 0, stream>>>(deg, norm, N_NODES);
    k_off<<<(N_NODES + 255) / 256, 256, 0, stream>>>(deg, row_ptr, cursor, gcount, N_NODES);
    k_scatter<<<(N_EDGES + 255) / 256, 256, 0, stream>>>(src, dst, cursor, csr_src, N_EDGES);
    k_aggnf<<<(N_NODES + 3) / 4, 256, 0, stream>>>(node_feats, norm, row_ptr, deg, csr_src,
                                                   aggnf, snorm, N_NODES);
    k_h0<<<(N_NODES * HID + 255) / 256, 256, 0, stream>>>(aggnf, snorm, norm, W0, b0,
                                                          B1, B2, N_NODES * HID);
    // layer 1
    k_agg<<<(N_NODES + 3) / 4, 256, 0, stream>>>(B2, row_ptr, deg, csr_src, B3, N_NODES);
    k_mv<<<(N_NODES + 63) / 64, 256, 0, stream>>>(B3, B1, W1, b1, norm, snorm, B4, B2, N_NODES);
    // layer 2
    k_agg<<<(N_NODES + 3) / 4, 256, 0, stream>>>(B2, row_ptr, deg, csr_src, B3, N_NODES);
    k_mv<<<(N_NODES + 63) / 64, 256, 0, stream>>>(B3, B4, W2, b2, norm, snorm, B1, nullptr, N_NODES);
    // edge path
    k_small<<<1, 256, 0, stream>>>(curr_emb, pay_emb, M0, C1, C2, P);
    k_combo<<<(15 * 15 * 7 * 64 + 255) / 256, 256, 0, stream>>>(C1, C2, P, bM0, T, 15 * 15 * 7 * 64);
    k_mv2<<<(N_NODES + 63) / 64, 512, 0, stream>>>(B1, M0, Ab, Bb, N_NODES);
    k_edge<<<(N_EDGES + 255) / 256, 256, 0, stream>>>(Ab, Bb, T, M0, M1, bM1, M2, bM2,
                                                      src, dst, pc, rc, pf, num, out, N_EDGES);
}